// Round 6
// baseline (518.430 us; speedup 1.0000x reference)
//
#include <hip/hip_runtime.h>

// QORNN: quantized orthogonal RNN — exact-integer recurrence.
// v9: one-output-per-lane, broadcast-h, reduce-free step.
// Model (consistent across v3/v5/v7/v8): v_dot4 issues ~4cy/wave64, so step =
// ~500cy issue (80 sdots/lane, the exact MAC count) + ~370cy serial exchange
// (write-drain + barrier + ds_read + reduce/modrelu chain), ~zero overlap at
// 1 wave/SIMD. v8 falsified the "unfilled read bubble" theory; v6 killed MFMA
// (matvec has one free index); v5/v7 killed TLP/batching (grid = row count).
// This round removes the last removable serial term: the quad k-split's
// qsum (2 DPP) + 3 cndmask selects between last sdot and modrelu.
//  - lane tid owns output tid; reads FULL h as 16 uniform ds_read_b128
//    (same addr across lanes -> broadcast, conflict-free; kills the 303K
//    bank conflicts of the k-split reads).
//  - z = eight 8-deep sdot chains + 7-add tree. Integer sum, order-only
//    change -> bit-exact. modrelu v3-verbatim. Barrier structure unchanged.

#define TSEQ 1024
#define IDIM 64
#define HDIM 256
#define ODIM 16

__device__ __forceinline__ int sdot4i8(int a, int b, int c) {
#if __has_builtin(__builtin_amdgcn_sdot4)
    return __builtin_amdgcn_sdot4(a, b, c, false);
#else
    int r = c;
    r += ((a << 24) >> 24) * ((b << 24) >> 24);
    r += ((a << 16) >> 24) * ((b << 16) >> 24);
    r += ((a << 8)  >> 24) * ((b << 8)  >> 24);
    r += (a >> 24) * (b >> 24);
    return r;
#endif
}

__device__ __forceinline__ int qpack4(float4 f, float s, float lo, float hi) {
    int a = (int)fminf(fmaxf(rintf(f.x * s), lo), hi);
    int b = (int)fminf(fmaxf(rintf(f.y * s), lo), hi);
    int c = (int)fminf(fmaxf(rintf(f.z * s), lo), hi);
    int d = (int)fminf(fmaxf(rintf(f.w * s), lo), hi);
    return (a & 255) | ((b & 255) << 8) | ((c & 255) << 16) | ((d & 255) << 24);
}

__global__ __launch_bounds__(256, 1)
void qornn_kernel(const float* __restrict__ x, const float* __restrict__ Wi,
                  const float* __restrict__ Wr, const float* __restrict__ Wo,
                  const float* __restrict__ bias, float* __restrict__ out) {
    __shared__ alignas(16) int xlds[TSEQ * 16 + 64]; // whole row, int8-packed (64KB + pad)
    __shared__ alignas(16) int wstage[8192];         // 32 KB staging; Wo resident after init
    __shared__ alignas(16) int hbuf[2][64];          // double-buffered h (256 int8 each)

    const int tid = threadIdx.x;
    const int brow = blockIdx.x;

    // ---- stage Wi [256 x 64] fp32 -> int8 (scale 8); lane keeps row tid ----
    {
        const float4* wi4 = (const float4*)Wi;
        #pragma unroll
        for (int it = 0; it < 16; ++it) {
            int flat = it * 256 + tid;
            wstage[flat] = qpack4(wi4[flat], 8.0f, -8.0f, 7.0f);
        }
    }
    __syncthreads();
    int4 wiq[4];   // wiq[r] = Wi[tid][r*16 .. r*16+15]
    {
        const int4* p = (const int4*)wstage;
        #pragma unroll
        for (int r = 0; r < 4; ++r) wiq[r] = p[tid * 4 + r];
    }
    __syncthreads();

    // ---- stage Wr [256 x 256] -> int8 in two halves; lane keeps full row tid ----
    int4 wr[16];   // wr[j] = Wr[tid][j*16 .. j*16+15]
    {
        const float4* wr4 = (const float4*)Wr;
        #pragma unroll
        for (int it = 0; it < 32; ++it) {
            int flat = it * 256 + tid;
            wstage[flat] = qpack4(wr4[flat], 8.0f, -8.0f, 7.0f);
        }
        __syncthreads();
        if (tid < 128) {                 // waves 0..1 (wave-uniform)
            const int4* p = (const int4*)wstage;
            #pragma unroll
            for (int j = 0; j < 16; ++j) wr[j] = p[tid * 16 + j];
        }
        __syncthreads();
        #pragma unroll
        for (int it = 0; it < 32; ++it) {
            int flat = it * 256 + tid;
            wstage[flat] = qpack4(wr4[8192 + flat], 8.0f, -8.0f, 7.0f);
        }
        __syncthreads();
        if (tid >= 128) {                // waves 2..3
            const int4* p = (const int4*)wstage;
            #pragma unroll
            for (int j = 0; j < 16; ++j) wr[j] = p[(tid - 128) * 16 + j];
        }
        __syncthreads();
    }

    // ---- stage Wo [16 x 256] -> int8, resident in wstage[0..1023] ----
    {
        const float4* wo4 = (const float4*)Wo;
        #pragma unroll
        for (int it = 0; it < 4; ++it) {
            int flat = it * 256 + tid;
            wstage[flat] = qpack4(wo4[flat], 8.0f, -8.0f, 7.0f);
        }
    }

    // ---- stage entire x row to LDS as int8 (scale 128) ----
    {
        const float4* rowf4 = (const float4*)(x + (size_t)brow * (TSEQ * IDIM));
        #pragma unroll 8
        for (int it = 0; it < 64; ++it) {
            int flat = it * 256 + tid;               // float4 idx == packed dword idx
            xlds[flat] = qpack4(rowf4[flat], 128.0f, -128.0f, 127.0f);
        }
    }
    if (tid < 64) hbuf[0][tid] = 0;                  // h0 = 0
    __syncthreads();

    const float bv = bias[tid];                      // bias for output tid

    // u accumulator for t=0: x_0 . Wi[tid] (uniform broadcast reads)
    int u;
    {
        const int4* xp = (const int4*)xlds;
        int s0 = 0, s1 = 0;
        #pragma unroll
        for (int r = 0; r < 2; ++r) {
            const int4 xx = xp[r];
            s0 = sdot4i8(xx.x, wiq[r].x, s0);
            s0 = sdot4i8(xx.y, wiq[r].y, s0);
            s0 = sdot4i8(xx.z, wiq[r].z, s0);
            s0 = sdot4i8(xx.w, wiq[r].w, s0);
        }
        #pragma unroll
        for (int r = 2; r < 4; ++r) {
            const int4 xx = xp[r];
            s1 = sdot4i8(xx.x, wiq[r].x, s1);
            s1 = sdot4i8(xx.y, wiq[r].y, s1);
            s1 = sdot4i8(xx.z, wiq[r].z, s1);
            s1 = sdot4i8(xx.w, wiq[r].w, s1);
        }
        u = s0 + s1;
    }

    // ---- main recurrence: 1024 steps, no global traffic, 1 barrier/step ----
    #pragma unroll 2
    for (int t = 0; t < TSEQ; ++t) {
        // full h_t, 16 uniform ds_read_b128 (broadcast, conflict-free)
        int4 hh[16];
        {
            const int4* hP = (const int4*)hbuf[t & 1];
            #pragma unroll
            for (int j = 0; j < 16; ++j) hh[j] = hP[j];
        }
        // x_{t+1}, 4 uniform reads (xlds padded so t=1023 is safe)
        int4 xn[4];
        #pragma unroll
        for (int r = 0; r < 4; ++r) xn[r] = ((const int4*)xlds)[(t + 1) * 4 + r];

        // z: eight 8-deep sdot chains (chain c covers j = c and c+8); a0 seeded u
        int a0 = u, a1 = 0, a2 = 0, a3 = 0, a4 = 0, a5 = 0, a6 = 0, a7 = 0;
        #pragma unroll
        for (int c = 0; c < 8; ++c) {
            int s = (c == 0) ? a0 : ((c == 1) ? a1 : (c == 2) ? a2 : (c == 3) ? a3
                  : (c == 4) ? a4 : (c == 5) ? a5 : (c == 6) ? a6 : a7);
            s = sdot4i8(hh[c].x, wr[c].x, s);
            s = sdot4i8(hh[c].y, wr[c].y, s);
            s = sdot4i8(hh[c].z, wr[c].z, s);
            s = sdot4i8(hh[c].w, wr[c].w, s);
            s = sdot4i8(hh[c + 8].x, wr[c + 8].x, s);
            s = sdot4i8(hh[c + 8].y, wr[c + 8].y, s);
            s = sdot4i8(hh[c + 8].z, wr[c + 8].z, s);
            s = sdot4i8(hh[c + 8].w, wr[c + 8].w, s);
            if (c == 0) a0 = s; else if (c == 1) a1 = s; else if (c == 2) a2 = s;
            else if (c == 3) a3 = s; else if (c == 4) a4 = s; else if (c == 5) a5 = s;
            else if (c == 6) a6 = s; else a7 = s;
        }

        // u for step t+1 (h-independent filler; two chains)
        int un;
        {
            int s0 = 0, s1 = 0;
            #pragma unroll
            for (int r = 0; r < 2; ++r) {
                s0 = sdot4i8(xn[r].x, wiq[r].x, s0);
                s0 = sdot4i8(xn[r].y, wiq[r].y, s0);
                s0 = sdot4i8(xn[r].z, wiq[r].z, s0);
                s0 = sdot4i8(xn[r].w, wiq[r].w, s0);
            }
            #pragma unroll
            for (int r = 2; r < 4; ++r) {
                s1 = sdot4i8(xn[r].x, wiq[r].x, s1);
                s1 = sdot4i8(xn[r].y, wiq[r].y, s1);
                s1 = sdot4i8(xn[r].z, wiq[r].z, s1);
                s1 = sdot4i8(xn[r].w, wiq[r].w, s1);
            }
            un = s0 + s1;
        }

        // combine tree (7 adds, depth 3) — no cross-lane ops, no selects
        const int z = ((a0 + a1) + (a2 + a3)) + ((a4 + a5) + (a6 + a7));

        // exact modrelu + 8-bit requantize (v3 arithmetic, verbatim)
        const float zf = (float)z;
        const float t1 = fmaf(fabsf(zf), 0.0009765625f, bv);
        const float t2 = fmaxf(t1, 0.0f);
        const float r  = rintf(t2 * 128.0f);
        const int vpos = (int)fminf(r, 127.0f);
        const int vneg = -(int)fminf(r, 128.0f);
        int hv = (z < 0) ? vneg : vpos;
        hv = (z == 0) ? 0 : hv;

        ((signed char*)hbuf[(t + 1) & 1])[tid] = (signed char)hv;

        u = un;
        __syncthreads();
    }

    // ---- epilogue: out[b, o] = h_last . Wo_row(o) / 1024  (h_1024 in hbuf[0]) ----
    if (tid < ODIM) {
        const int4* wo = (const int4*)wstage;
        const int4* hl = (const int4*)hbuf[0];
        int a0 = 0, a1 = 0, a2 = 0, a3 = 0;
        #pragma unroll
        for (int i = 0; i < 16; ++i) {
            int4 w4 = wo[tid * 16 + i];
            int4 h4 = hl[i];
            a0 = sdot4i8(h4.x, w4.x, a0);
            a1 = sdot4i8(h4.y, w4.y, a1);
            a2 = sdot4i8(h4.z, w4.z, a2);
            a3 = sdot4i8(h4.w, w4.w, a3);
        }
        out[brow * ODIM + tid] = (float)((a0 + a1) + (a2 + a3)) * 0.0009765625f;
    }
}

extern "C" void kernel_launch(void* const* d_in, const int* in_sizes, int n_in,
                              void* d_out, int out_size, void* d_ws, size_t ws_size,
                              hipStream_t stream) {
    const float* x  = (const float*)d_in[0];   // [B, T, I]
    const float* Wi = (const float*)d_in[1];   // [H, I]
    const float* Wr = (const float*)d_in[2];   // [H, H]
    const float* Wo = (const float*)d_in[3];   // [O, H]
    const float* b  = (const float*)d_in[4];   // [H]
    float* out = (float*)d_out;                // [B, O]

    const int B = in_sizes[0] / (TSEQ * IDIM); // 256
    qornn_kernel<<<B, HDIM, 0, stream>>>(x, Wi, Wr, Wo, b, out);
}

// Round 7
// 421.137 us; speedup vs baseline: 1.2310x; 1.2310x over previous
//
#include <hip/hip_runtime.h>

// QORNN: quantized orthogonal RNN — exact-integer recurrence.
// v10 = v3 (fastest verified, 369us dispatch) + u-precompute on the MFMA pipe.
// Model (v3..v9-consistent): step ~870cy = ~500 issue (80 sdots x 4cy + misc)
// + ~370 serial exchange. v8: reorder can't fill bubbles; v9: reads can't get
// cheaper (broadcast-h quadrupled LDS traffic, regressed). Remaining lever:
// u = x.Wi is h-independent AND time-batchable -> real GEMM tile, unlike v6's
// broadcast-matvec. Every 16 steps: 4x mfma_i32_16x16x64_i8 per wave computes
// u[16 timesteps][wave's 64 rows] (B = 16 DISTINCT timestep columns, no waste;
// A/B/C layouts are the ones v6 verified on HW with absmax 0.0) into a
// double-buffered LDS table. Removes 16 sdots/lane/step (~64cy) for ~4cy/step
// amortized MFMA cost. Integer-exact: same dots, MFMA i32 accumulate, add
// order commutative. Race-free: chunk c+1 writes buf (c^1), first read is
// >=16 steps (16 barriers) later. Everything else v3-verbatim.

#define TSEQ 1024
#define IDIM 64
#define HDIM 256
#define ODIM 16
#define USTRIDE 260              // 256 + 4 pad: spreads u-write banks
#define UBUF 4160                // 16 * USTRIDE

using i32x4 = __attribute__((ext_vector_type(4))) int;

__device__ __forceinline__ int sdot4i8(int a, int b, int c) {
#if __has_builtin(__builtin_amdgcn_sdot4)
    return __builtin_amdgcn_sdot4(a, b, c, false);
#else
    int r = c;
    r += ((a << 24) >> 24) * ((b << 24) >> 24);
    r += ((a << 16) >> 24) * ((b << 16) >> 24);
    r += ((a << 8)  >> 24) * ((b << 8)  >> 24);
    r += (a >> 24) * (b >> 24);
    return r;
#endif
}

__device__ __forceinline__ int qpack4(float4 f, float s, float lo, float hi) {
    int a = (int)fminf(fmaxf(rintf(f.x * s), lo), hi);
    int b = (int)fminf(fmaxf(rintf(f.y * s), lo), hi);
    int c = (int)fminf(fmaxf(rintf(f.z * s), lo), hi);
    int d = (int)fminf(fmaxf(rintf(f.w * s), lo), hi);
    return (a & 255) | ((b & 255) << 8) | ((c & 255) << 16) | ((d & 255) << 24);
}

// quad butterfly sum: all 4 lanes of each quad end with the quad-sum
__device__ __forceinline__ int qsum(int v) {
    v += __builtin_amdgcn_update_dpp(0, v, 0xB1, 0xF, 0xF, true); // quad_perm xor1
    v += __builtin_amdgcn_update_dpp(0, v, 0x4E, 0xF, 0xF, true); // quad_perm xor2
    return v;
}

__global__ __launch_bounds__(256, 1)
void qornn_kernel(const float* __restrict__ x, const float* __restrict__ Wi,
                  const float* __restrict__ Wr, const float* __restrict__ Wo,
                  const float* __restrict__ bias, float* __restrict__ out) {
    // x row + 16 extra rows so the final (unused) chunk-64 B-frag read stays
    // in bounds: (1024+16) rows * 16 dwords
    __shared__ alignas(16) int xlds[(TSEQ + 16) * 16];
    __shared__ alignas(16) int ustage[2 * UBUF];     // u dbuf (33KB); weight scratch pre-loop
    __shared__ alignas(16) int wolds[1024];          // Wo int8, resident
    __shared__ alignas(16) int hbuf[2][64];          // double-buffered h (256 int8 each)

    const int tid = threadIdx.x;
    const int brow = blockIdx.x;
    const int w    = tid >> 6;          // wave 0..3
    const int l    = tid & 63;
    const int q    = l & 3;             // k-quarter this lane reads; also its output slot
    const int m16  = l >> 2;            // quad id in wave
    const int obase = w * 64 + m16 * 4; // outputs obase..obase+3 (obase+q == tid)
    const int lm   = l & 15;            // MFMA: A row in tile / C col (timestep)
    const int kg   = l >> 4;            // MFMA: k-group / C row-group

    // ---- stage Wi [256 x 64] fp32 -> int8 (scale 8); extract MFMA A-frags ----
    {
        const float4* wi4 = (const float4*)Wi;
        #pragma unroll
        for (int it = 0; it < 16; ++it) {
            int flat = it * 256 + tid;
            ustage[flat] = qpack4(wi4[flat], 8.0f, -8.0f, 7.0f);
        }
    }
    __syncthreads();
    i32x4 wiA[4];  // wiA[tt] = Wi[w*64 + tt*16 + lm][kg*16 .. kg*16+15]
    {
        const i32x4* p = (const i32x4*)ustage;
        #pragma unroll
        for (int tt = 0; tt < 4; ++tt)
            wiA[tt] = p[(w * 64 + tt * 16 + lm) * 4 + kg];
    }
    __syncthreads();

    // ---- stage Wr [256 x 256] -> int8 in two halves; lane keeps 4 quarter-rows ----
    int4 wr[16];   // wr[i*4+r] = Wr[obase+i][q*64 + r*16 .. +15]
    {
        const float4* wr4 = (const float4*)Wr;
        #pragma unroll
        for (int it = 0; it < 32; ++it) {
            int flat = it * 256 + tid;
            ustage[flat] = qpack4(wr4[flat], 8.0f, -8.0f, 7.0f);
        }
        __syncthreads();
        if (obase < 128) {
            const int4* p = (const int4*)ustage;
            #pragma unroll
            for (int i = 0; i < 4; ++i)
                #pragma unroll
                for (int r = 0; r < 4; ++r)
                    wr[i * 4 + r] = p[(obase + i) * 16 + q * 4 + r];
        }
        __syncthreads();
        #pragma unroll
        for (int it = 0; it < 32; ++it) {
            int flat = it * 256 + tid;
            ustage[flat] = qpack4(wr4[8192 + flat], 8.0f, -8.0f, 7.0f);
        }
        __syncthreads();
        if (obase >= 128) {
            const int4* p = (const int4*)ustage;
            #pragma unroll
            for (int i = 0; i < 4; ++i)
                #pragma unroll
                for (int r = 0; r < 4; ++r)
                    wr[i * 4 + r] = p[(obase - 128 + i) * 16 + q * 4 + r];
        }
        __syncthreads();
    }

    // ---- stage Wo [16 x 256] -> int8, resident in wolds ----
    {
        const float4* wo4 = (const float4*)Wo;
        #pragma unroll
        for (int it = 0; it < 4; ++it) {
            int flat = it * 256 + tid;
            wolds[flat] = qpack4(wo4[flat], 8.0f, -8.0f, 7.0f);
        }
    }

    // ---- stage entire x row to LDS as int8 (scale 128) ----
    {
        const float4* rowf4 = (const float4*)(x + (size_t)brow * (TSEQ * IDIM));
        #pragma unroll 8
        for (int it = 0; it < 64; ++it) {
            int flat = it * 256 + tid;               // float4 idx == packed dword idx
            xlds[flat] = qpack4(rowf4[flat], 128.0f, -128.0f, 127.0f);
        }
    }
    if (tid < 64) hbuf[0][tid] = 0;                  // h0 = 0
    __syncthreads();

    // ---- u chunk 0 (t=0..15) via MFMA into ustage buf 0 ----
    // B-frag: x[t0+lm][kg*16..+15]; C: lane holds rows (w*64+tt*16+kg*4..+3),
    // col lm  =>  ustage[lm*USTRIDE + row] (4B x 4, b128-aligned)
    {
        const i32x4 bf = *(const i32x4*)&xlds[lm * 16 + kg * 4];
        #pragma unroll
        for (int tt = 0; tt < 4; ++tt) {
            i32x4 acc = {0, 0, 0, 0};
            acc = __builtin_amdgcn_mfma_i32_16x16x64_i8(wiA[tt], bf, acc, 0, 0, 0);
            *(i32x4*)&ustage[lm * USTRIDE + w * 64 + tt * 16 + kg * 4] = acc;
        }
    }

    const float bv = bias[tid];                      // bias for output tid (== obase+q)
    const bool qb0 = (q & 1) != 0;
    const bool qb1 = (q & 2) != 0;
    __syncthreads();

    // ---- main recurrence: 1024 steps, 1 barrier/step, no global traffic ----
    #pragma unroll 2
    for (int t = 0; t < TSEQ; ++t) {
        const int cb = (t >> 4) & 1;
        // u_t[tid] read early: latency hidden under the 64 sdots
        const int ut = ustage[cb * UBUF + (t & 15) * USTRIDE + tid];

        // this lane's k-quarter of h_t
        int4 hh[4];
        {
            const int4* hP = (const int4*)hbuf[t & 1];
            #pragma unroll
            for (int r = 0; r < 4; ++r) hh[r] = hP[q * 4 + r];
        }

        // next-chunk u via MFMA (uniform scalar branch, once per 16 steps;
        // h-independent -> fills stall windows; writes complete by next barrier)
        if ((t & 15) == 0) {
            const int t0 = t + 16;
            const i32x4 bf = *(const i32x4*)&xlds[(t0 + lm) * 16 + kg * 4];
            #pragma unroll
            for (int tt = 0; tt < 4; ++tt) {
                i32x4 acc = {0, 0, 0, 0};
                acc = __builtin_amdgcn_mfma_i32_16x16x64_i8(wiA[tt], bf, acc, 0, 0, 0);
                *(i32x4*)&ustage[(cb ^ 1) * UBUF + lm * USTRIDE + w * 64 + tt * 16 + kg * 4] = acc;
            }
        }

        // z partials: two 8-deep chains per output (v3 structure, unseeded)
        int za[4], zb[4];
        #pragma unroll
        for (int i = 0; i < 4; ++i) {
            int s0 = 0;
            s0 = sdot4i8(hh[0].x, wr[i * 4 + 0].x, s0);
            s0 = sdot4i8(hh[0].y, wr[i * 4 + 0].y, s0);
            s0 = sdot4i8(hh[0].z, wr[i * 4 + 0].z, s0);
            s0 = sdot4i8(hh[0].w, wr[i * 4 + 0].w, s0);
            s0 = sdot4i8(hh[1].x, wr[i * 4 + 1].x, s0);
            s0 = sdot4i8(hh[1].y, wr[i * 4 + 1].y, s0);
            s0 = sdot4i8(hh[1].z, wr[i * 4 + 1].z, s0);
            s0 = sdot4i8(hh[1].w, wr[i * 4 + 1].w, s0);
            int s1 = 0;
            s1 = sdot4i8(hh[2].x, wr[i * 4 + 2].x, s1);
            s1 = sdot4i8(hh[2].y, wr[i * 4 + 2].y, s1);
            s1 = sdot4i8(hh[2].z, wr[i * 4 + 2].z, s1);
            s1 = sdot4i8(hh[2].w, wr[i * 4 + 2].w, s1);
            s1 = sdot4i8(hh[3].x, wr[i * 4 + 3].x, s1);
            s1 = sdot4i8(hh[3].y, wr[i * 4 + 3].y, s1);
            s1 = sdot4i8(hh[3].z, wr[i * 4 + 3].z, s1);
            s1 = sdot4i8(hh[3].w, wr[i * 4 + 3].w, s1);
            za[i] = s0; zb[i] = s1;
        }

        // quad-reduce all 4 outputs; lane q keeps output obase+q; add u last
        const int z0 = qsum(za[0] + zb[0]);
        const int z1 = qsum(za[1] + zb[1]);
        const int z2 = qsum(za[2] + zb[2]);
        const int z3 = qsum(za[3] + zb[3]);
        const int zlo = qb0 ? z1 : z0;
        const int zhi = qb0 ? z3 : z2;
        const int z   = (qb1 ? zhi : zlo) + ut;

        // exact modrelu + 8-bit requantize (v3 arithmetic, verbatim)
        const float zf = (float)z;
        const float t1 = fmaf(fabsf(zf), 0.0009765625f, bv);
        const float t2 = fmaxf(t1, 0.0f);
        const float r  = rintf(t2 * 128.0f);
        const int vpos = (int)fminf(r, 127.0f);
        const int vneg = -(int)fminf(r, 128.0f);
        int hv = (z < 0) ? vneg : vpos;
        hv = (z == 0) ? 0 : hv;

        ((signed char*)hbuf[(t + 1) & 1])[tid] = (signed char)hv;

        __syncthreads();
    }

    // ---- epilogue: out[b, o] = h_last . Wo_row(o) / 1024  (h_1024 in hbuf[0]) ----
    if (tid < ODIM) {
        const int4* wo = (const int4*)wolds;
        const int4* hl = (const int4*)hbuf[0];
        int a0 = 0, a1 = 0, a2 = 0, a3 = 0;
        #pragma unroll
        for (int i = 0; i < 16; ++i) {
            int4 w4 = wo[tid * 16 + i];
            int4 h4 = hl[i];
            a0 = sdot4i8(h4.x, w4.x, a0);
            a1 = sdot4i8(h4.y, w4.y, a1);
            a2 = sdot4i8(h4.z, w4.z, a2);
            a3 = sdot4i8(h4.w, w4.w, a3);
        }
        out[brow * ODIM + tid] = (float)((a0 + a1) + (a2 + a3)) * 0.0009765625f;
    }
}

extern "C" void kernel_launch(void* const* d_in, const int* in_sizes, int n_in,
                              void* d_out, int out_size, void* d_ws, size_t ws_size,
                              hipStream_t stream) {
    const float* x  = (const float*)d_in[0];   // [B, T, I]
    const float* Wi = (const float*)d_in[1];   // [H, I]
    const float* Wr = (const float*)d_in[2];   // [H, H]
    const float* Wo = (const float*)d_in[3];   // [O, H]
    const float* b  = (const float*)d_in[4];   // [H]
    float* out = (float*)d_out;                // [B, O]

    const int B = in_sizes[0] / (TSEQ * IDIM); // 256
    qornn_kernel<<<B, HDIM, 0, stream>>>(x, Wi, Wr, Wo, b, out);
}

// Round 9
// 414.112 us; speedup vs baseline: 1.2519x; 1.0170x over previous
//
#include <hip/hip_runtime.h>

// QORNN: quantized orthogonal RNN — exact-integer recurrence.
// v12 = v3 VERBATIM + shortened modrelu tail, CONSTANT FIXED.
// v4/v11 post-mortem: their shared absmax=5.17 failure was a folding slip —
// z_int is 1024x the float z, so folding the x128 requantize into the fma
// needs |z_int| * (128/1024) = |z_int| * 2^-3 = 0.125f. v4/v11 used 2^-7
// (0.0078125f): magnitude term 16x too small. With 0.125f the transform is
// bit-exact: fma exact-product + single RNE rounding commutes with pow2
// scaling; bv*128 exact; z>0: clamp(r,-128,127)==min(r,127); z<0:
// clamp(-r,..) == -min(r,128); z==0 -> 0. Matches ref's clip(round(.)).
// Model (v3..v10): step ~865cy = ~500cy issue (hidden; v10) + ~365cy serial
// exchange. This shaves ~15cy off the modrelu link of that serial tail —
// the last attackable term. If flat: declare roofline.

#define TSEQ 1024
#define IDIM 64
#define HDIM 256
#define ODIM 16

__device__ __forceinline__ int sdot4i8(int a, int b, int c) {
#if __has_builtin(__builtin_amdgcn_sdot4)
    return __builtin_amdgcn_sdot4(a, b, c, false);
#else
    int r = c;
    r += ((a << 24) >> 24) * ((b << 24) >> 24);
    r += ((a << 16) >> 24) * ((b << 16) >> 24);
    r += ((a << 8)  >> 24) * ((b << 8)  >> 24);
    r += (a >> 24) * (b >> 24);
    return r;
#endif
}

__device__ __forceinline__ int qpack4(float4 f, float s, float lo, float hi) {
    int a = (int)fminf(fmaxf(rintf(f.x * s), lo), hi);
    int b = (int)fminf(fmaxf(rintf(f.y * s), lo), hi);
    int c = (int)fminf(fmaxf(rintf(f.z * s), lo), hi);
    int d = (int)fminf(fmaxf(rintf(f.w * s), lo), hi);
    return (a & 255) | ((b & 255) << 8) | ((c & 255) << 16) | ((d & 255) << 24);
}

// quad butterfly sum: all 4 lanes of each quad end with the quad-sum
__device__ __forceinline__ int qsum(int v) {
    v += __builtin_amdgcn_update_dpp(0, v, 0xB1, 0xF, 0xF, true); // quad_perm xor1
    v += __builtin_amdgcn_update_dpp(0, v, 0x4E, 0xF, 0xF, true); // quad_perm xor2
    return v;
}

__global__ __launch_bounds__(256, 1)
void qornn_kernel(const float* __restrict__ x, const float* __restrict__ Wi,
                  const float* __restrict__ Wr, const float* __restrict__ Wo,
                  const float* __restrict__ bias, float* __restrict__ out) {
    __shared__ alignas(16) int xlds[TSEQ * 16 + 16]; // whole row, int8-packed (64KB + pad)
    __shared__ alignas(16) int wstage[8192];         // 32 KB staging; Wo resident after init
    __shared__ alignas(16) int hbuf[2][64];          // double-buffered h (256 int8 each)

    const int tid = threadIdx.x;
    const int brow = blockIdx.x;
    const int w    = tid >> 6;          // wave 0..3
    const int l    = tid & 63;
    const int q    = l & 3;             // k-quarter this lane reads; also its output slot
    const int m16  = l >> 2;            // quad id in wave
    const int obase = w * 64 + m16 * 4; // outputs obase..obase+3 (obase+q == tid)

    // ---- stage Wi [256 x 64] fp32 -> int8 (scale 8); lane keeps 4 quarter-rows ----
    {
        const float4* wi4 = (const float4*)Wi;
        #pragma unroll
        for (int it = 0; it < 16; ++it) {
            int flat = it * 256 + tid;
            wstage[flat] = qpack4(wi4[flat], 8.0f, -8.0f, 7.0f);
        }
    }
    __syncthreads();
    int4 wiq[4];   // wiq[i] = Wi[obase+i][q*16 .. q*16+15]
    {
        const int4* p = (const int4*)wstage;
        #pragma unroll
        for (int i = 0; i < 4; ++i) wiq[i] = p[(obase + i) * 4 + q];
    }
    __syncthreads();

    // ---- stage Wr [256 x 256] -> int8 in two halves; lane keeps 4 quarter-rows ----
    int4 wr[16];   // wr[i*4+r] = Wr[obase+i][q*64 + r*16 .. +15]
    {
        const float4* wr4 = (const float4*)Wr;
        #pragma unroll
        for (int it = 0; it < 32; ++it) {
            int flat = it * 256 + tid;
            wstage[flat] = qpack4(wr4[flat], 8.0f, -8.0f, 7.0f);
        }
        __syncthreads();
        if (obase < 128) {
            const int4* p = (const int4*)wstage;
            #pragma unroll
            for (int i = 0; i < 4; ++i)
                #pragma unroll
                for (int r = 0; r < 4; ++r)
                    wr[i * 4 + r] = p[(obase + i) * 16 + q * 4 + r];
        }
        __syncthreads();
        #pragma unroll
        for (int it = 0; it < 32; ++it) {
            int flat = it * 256 + tid;
            wstage[flat] = qpack4(wr4[8192 + flat], 8.0f, -8.0f, 7.0f);
        }
        __syncthreads();
        if (obase >= 128) {
            const int4* p = (const int4*)wstage;
            #pragma unroll
            for (int i = 0; i < 4; ++i)
                #pragma unroll
                for (int r = 0; r < 4; ++r)
                    wr[i * 4 + r] = p[(obase - 128 + i) * 16 + q * 4 + r];
        }
        __syncthreads();
    }

    // ---- stage Wo [16 x 256] -> int8, resident in wstage[0..1023] ----
    {
        const float4* wo4 = (const float4*)Wo;
        #pragma unroll
        for (int it = 0; it < 4; ++it) {
            int flat = it * 256 + tid;
            wstage[flat] = qpack4(wo4[flat], 8.0f, -8.0f, 7.0f);
        }
    }

    // ---- stage entire x row to LDS as int8 (scale 128) ----
    {
        const float4* rowf4 = (const float4*)(x + (size_t)brow * (TSEQ * IDIM));
        #pragma unroll 8
        for (int it = 0; it < 64; ++it) {
            int flat = it * 256 + tid;               // float4 idx == packed dword idx
            xlds[flat] = qpack4(rowf4[flat], 128.0f, -128.0f, 127.0f);
        }
    }
    if (tid < 64) hbuf[0][tid] = 0;                  // h0 = 0
    __syncthreads();

    // bias pre-scaled by 128 (exact pow2 mul). Requantize target:
    // r = rint(max(|z_int|*2^-3 + 128b, 0))  ==  128 * ref's rint path,
    // since z_int = 1024*z_f and 1024/128 = 8 -> 128*|z_f| = |z_int|*0.125.
    const float bv128 = bias[tid] * 128.0f;
    const bool qb0 = (q & 1) != 0;
    const bool qb1 = (q & 2) != 0;

    // u accumulators for t=0 (x_t . Wi quarter-rows)
    int u[4];
    {
        const int4 xx = ((const int4*)xlds)[q];
        #pragma unroll
        for (int i = 0; i < 4; ++i) {
            int s = sdot4i8(xx.x, wiq[i].x, 0);
            s = sdot4i8(xx.y, wiq[i].y, s);
            s = sdot4i8(xx.z, wiq[i].z, s);
            u[i] = sdot4i8(xx.w, wiq[i].w, s);
        }
    }

    // ---- main recurrence: 1024 steps, no global traffic, 1 barrier/step ----
    #pragma unroll 2
    for (int t = 0; t < TSEQ; ++t) {
        // read this lane's k-quarter of h_t
        int4 hh[4];
        {
            const int4* hP = (const int4*)hbuf[t & 1];
            #pragma unroll
            for (int r = 0; r < 4; ++r) hh[r] = hP[q * 4 + r];
        }
        // prefetch next x quarter (xlds padded so t=1023 read is safe)
        const int4 xn = ((const int4*)xlds)[(t + 1) * 4 + q];

        // z partials: two chains per output, seeded with u[i]
        int za[4], zb[4];
        #pragma unroll
        for (int i = 0; i < 4; ++i) {
            int s0 = u[i];
            s0 = sdot4i8(hh[0].x, wr[i * 4 + 0].x, s0);
            s0 = sdot4i8(hh[0].y, wr[i * 4 + 0].y, s0);
            s0 = sdot4i8(hh[0].z, wr[i * 4 + 0].z, s0);
            s0 = sdot4i8(hh[0].w, wr[i * 4 + 0].w, s0);
            s0 = sdot4i8(hh[1].x, wr[i * 4 + 1].x, s0);
            s0 = sdot4i8(hh[1].y, wr[i * 4 + 1].y, s0);
            s0 = sdot4i8(hh[1].z, wr[i * 4 + 1].z, s0);
            s0 = sdot4i8(hh[1].w, wr[i * 4 + 1].w, s0);
            int s1 = 0;
            s1 = sdot4i8(hh[2].x, wr[i * 4 + 2].x, s1);
            s1 = sdot4i8(hh[2].y, wr[i * 4 + 2].y, s1);
            s1 = sdot4i8(hh[2].z, wr[i * 4 + 2].z, s1);
            s1 = sdot4i8(hh[2].w, wr[i * 4 + 2].w, s1);
            s1 = sdot4i8(hh[3].x, wr[i * 4 + 3].x, s1);
            s1 = sdot4i8(hh[3].y, wr[i * 4 + 3].y, s1);
            s1 = sdot4i8(hh[3].z, wr[i * 4 + 3].z, s1);
            s1 = sdot4i8(hh[3].w, wr[i * 4 + 3].w, s1);
            za[i] = s0; zb[i] = s1;
        }
        // u for step t+1 (independent of h -> fills latency bubbles)
        int un[4];
        #pragma unroll
        for (int i = 0; i < 4; ++i) {
            int s = sdot4i8(xn.x, wiq[i].x, 0);
            s = sdot4i8(xn.y, wiq[i].y, s);
            s = sdot4i8(xn.z, wiq[i].z, s);
            un[i] = sdot4i8(xn.w, wiq[i].w, s);
        }

        // quad-reduce all 4 outputs, then lane q keeps output obase+q only
        const int z0 = qsum(za[0] + zb[0]);
        const int z1 = qsum(za[1] + zb[1]);
        const int z2 = qsum(za[2] + zb[2]);
        const int z3 = qsum(za[3] + zb[3]);
        const int zlo = qb0 ? z1 : z0;
        const int zhi = qb0 ? z3 : z2;
        const int z   = qb1 ? zhi : zlo;

        // exact modrelu + 8-bit requantize (shortened tail, FIXED 0.125f)
        const float zf = (float)z;
        const float t1 = fmaf(fabsf(zf), 0.125f, bv128);
        const float r  = rintf(fmaxf(t1, 0.0f));
        const float sf = (z < 0) ? -r : r;
        const float cf = fminf(fmaxf(sf, -128.0f), 127.0f);   // fuses to v_med3_f32
        int hv = (int)cf;
        hv = (z == 0) ? 0 : hv;

        ((signed char*)hbuf[(t + 1) & 1])[tid] = (signed char)hv;

        #pragma unroll
        for (int i = 0; i < 4; ++i) u[i] = un[i];
        __syncthreads();
    }

    // ---- epilogue: out[b, o] = h_last . Wo_row(o) / 1024  (h_1024 in hbuf[0]) ----
    if (tid < ODIM) {
        const int4* wo = (const int4*)wstage;
        const int4* hl = (const int4*)hbuf[0];
        int a0 = 0, a1 = 0, a2 = 0, a3 = 0;
        #pragma unroll
        for (int i = 0; i < 16; ++i) {
            int4 w4 = wo[tid * 16 + i];
            int4 h4 = hl[i];
            a0 = sdot4i8(h4.x, w4.x, a0);
            a1 = sdot4i8(h4.y, w4.y, a1);
            a2 = sdot4i8(h4.z, w4.z, a2);
            a3 = sdot4i8(h4.w, w4.w, a3);
        }
        out[brow * ODIM + tid] = (float)((a0 + a1) + (a2 + a3)) * 0.0009765625f;
    }
}

extern "C" void kernel_launch(void* const* d_in, const int* in_sizes, int n_in,
                              void* d_out, int out_size, void* d_ws, size_t ws_size,
                              hipStream_t stream) {
    const float* x  = (const float*)d_in[0];   // [B, T, I]
    const float* Wi = (const float*)d_in[1];   // [H, I]
    const float* Wr = (const float*)d_in[2];   // [H, H]
    const float* Wo = (const float*)d_in[3];   // [O, H]
    const float* b  = (const float*)d_in[4];   // [H]
    float* out = (float*)d_out;                // [B, O]

    const int B = in_sizes[0] / (TSEQ * IDIM); // 256
    qornn_kernel<<<B, HDIM, 0, stream>>>(x, Wi, Wr, Wo, b, out);
}